// Round 1
// baseline (547.100 us; speedup 1.0000x reference)
//
#include <hip/hip_runtime.h>

// PosteriorHiddenTreeMarkovModel — MI355X / gfx950
// Tree: BR=3, DEPTH=7, NT=64 trees, NPT=3280 nodes/tree, DIM=209920.
// C=8 states, G=8 generators, M=128 symbols.
// Strategy: one block per tree (64 blocks x 256 threads). Softmaxed params
// (+ logs) live in LDS. beta/eps share one ws buffer (eps overwrites beta
// in place during the down pass); t_beta stored for internal nodes only.
// ell is never materialized: per-thread register accum -> block reduce.

namespace {

constexpr int kNT    = 64;
constexpr int kNPT   = 3280;   // OFF[8]
constexpr int kNINT  = 1093;   // OFF[7] = internal nodes per tree
constexpr int kLeaf0 = 1093;

__global__ __launch_bounds__(256)
void phtmm_kernel(const float* __restrict__ lamA,   // (8,8,3,8)
                  const float* __restrict__ lamB,   // (8,128,8)
                  const float* __restrict__ lamPi,  // (8,3,8)
                  const float* __restrict__ lamSP,  // (3,8)
                  const int*   __restrict__ x,      // (DIM,)
                  float* __restrict__ out,          // (64,8)
                  float* __restrict__ beta,         // DIM*64 (beta, then eps in place)
                  float* __restrict__ tbeta)        // NT*1093*64
{
    const int t   = blockIdx.x;
    const int tid = threadIdx.x;
    const int OFFS[9] = {0, 1, 4, 13, 40, 121, 364, 1093, 3280};

    __shared__ float sA[1536];   // softmax(A) [i][j][p][g]
    __shared__ float sLA[1536];  // log softmax(A)
    __shared__ float sBm[8192];  // softmax(B over m) [c][m][g]
    __shared__ float sPi[192];   // softmax(Pi over c) [c][p][g]
    __shared__ float sLPi[192];
    __shared__ float sSP[24];    // softmax(SP over p) [p][g]
    __shared__ float sLSP[24];
    __shared__ float sred[2048]; // block reduction

    // ---------- softmaxes into LDS ----------
    // A: softmax over axis 0 (i), per (j,p,g): 192 columns of 8
    for (int col = tid; col < 192; col += 256) {
        int j = col / 24; int rem = col - j * 24; int p = rem >> 3; int g = rem & 7;
        float v[8]; float mx = -1e30f;
        #pragma unroll
        for (int i = 0; i < 8; ++i) {
            v[i] = lamA[((i * 8 + j) * 3 + p) * 8 + g];
            mx = fmaxf(mx, v[i]);
        }
        float s = 0.f;
        #pragma unroll
        for (int i = 0; i < 8; ++i) { v[i] = expf(v[i] - mx); s += v[i]; }
        float inv = 1.f / s;
        #pragma unroll
        for (int i = 0; i < 8; ++i) {
            int idx = ((i * 8 + j) * 3 + p) * 8 + g;
            float sm = v[i] * inv;
            sA[idx]  = sm;
            sLA[idx] = logf(sm);
        }
    }
    // Bm: softmax over axis 1 (m=128), per (c,g): 64 rows
    for (int row = tid; row < 64; row += 256) {
        int c = row >> 3; int g = row & 7;
        float mx = -1e30f;
        for (int m = 0; m < 128; ++m)
            mx = fmaxf(mx, lamB[(c * 128 + m) * 8 + g]);
        float s = 0.f;
        for (int m = 0; m < 128; ++m)
            s += expf(lamB[(c * 128 + m) * 8 + g] - mx);
        float inv = 1.f / s;
        for (int m = 0; m < 128; ++m) {
            int idx = (c * 128 + m) * 8 + g;
            sBm[idx] = expf(lamB[idx] - mx) * inv;
        }
    }
    // Pi: softmax over axis 0 (c), per (p,g): 24 columns
    for (int col = tid; col < 24; col += 256) {
        int p = col >> 3; int g = col & 7;
        float v[8]; float mx = -1e30f;
        #pragma unroll
        for (int c = 0; c < 8; ++c) {
            v[c] = lamPi[(c * 3 + p) * 8 + g];
            mx = fmaxf(mx, v[c]);
        }
        float s = 0.f;
        #pragma unroll
        for (int c = 0; c < 8; ++c) { v[c] = expf(v[c] - mx); s += v[c]; }
        float inv = 1.f / s;
        #pragma unroll
        for (int c = 0; c < 8; ++c) {
            int idx = (c * 3 + p) * 8 + g;
            float sm = v[c] * inv;
            sPi[idx]  = sm;
            sLPi[idx] = logf(sm);
        }
    }
    // SP: softmax over axis 0 (p=3), per g
    if (tid < 8) {
        int g = tid;
        float v0 = lamSP[g], v1 = lamSP[8 + g], v2 = lamSP[16 + g];
        float mx = fmaxf(v0, fmaxf(v1, v2));
        float e0 = expf(v0 - mx), e1 = expf(v1 - mx), e2 = expf(v2 - mx);
        float inv = 1.f / (e0 + e1 + e2);
        sSP[g]      = e0 * inv; sSP[8 + g]  = e1 * inv; sSP[16 + g] = e2 * inv;
        sLSP[g]      = logf(e0 * inv);
        sLSP[8 + g]  = logf(e1 * inv);
        sLSP[16 + g] = logf(e2 * inv);
    }
    __syncthreads();

    // ---------- up pass: leaves ----------
    for (int loc = kLeaf0 + tid; loc < kNPT; loc += 256) {
        int node = t * kNPT + loc;
        int p = (loc - kLeaf0) % 3;
        int xv = x[node];
        float v[8][8]; float sg[8];
        #pragma unroll
        for (int g = 0; g < 8; ++g) sg[g] = 0.f;
        #pragma unroll
        for (int c = 0; c < 8; ++c)
            #pragma unroll
            for (int g = 0; g < 8; ++g) {
                float val = sPi[(c * 3 + p) * 8 + g] * sBm[(c * 128 + xv) * 8 + g];
                v[c][g] = val; sg[g] += val;
            }
        float ig[8];
        #pragma unroll
        for (int g = 0; g < 8; ++g) ig[g] = 1.f / sg[g];
        float* bp = beta + (size_t)node * 64;
        #pragma unroll
        for (int c = 0; c < 8; ++c)
            #pragma unroll
            for (int g = 0; g < 8; ++g)
                bp[c * 8 + g] = v[c][g] * ig[g];
    }
    __syncthreads();

    // ---------- up pass: internal levels (parents at level d-1) ----------
    for (int d = 7; d >= 1; --d) {
        int pbase = OFFS[d - 1];
        int pcount = OFFS[d] - OFFS[d - 1];
        int cbase = OFFS[d];
        for (int pi = tid; pi < pcount; pi += 256) {
            int locp = pbase + pi;
            int nodep = t * kNPT + locp;
            float acc[8][8];
            #pragma unroll
            for (int i = 0; i < 8; ++i)
                #pragma unroll
                for (int g = 0; g < 8; ++g) acc[i][g] = 0.f;
            int c0 = cbase + 3 * pi;
            #pragma unroll
            for (int k = 0; k < 3; ++k) {   // child pos == k
                const float* bc = beta + (size_t)(t * kNPT + c0 + k) * 64;
                float bj[8][8];
                #pragma unroll
                for (int j = 0; j < 8; ++j)
                    #pragma unroll
                    for (int g = 0; g < 8; ++g) bj[j][g] = bc[j * 8 + g];
                #pragma unroll
                for (int i = 0; i < 8; ++i)
                    #pragma unroll
                    for (int g = 0; g < 8; ++g) {
                        float s = 0.f;
                        #pragma unroll
                        for (int j = 0; j < 8; ++j)
                            s += sA[((i * 8 + j) * 3 + k) * 8 + g] * bj[j][g];
                        acc[i][g] += sSP[k * 8 + g] * s;
                    }
            }
            float* tb = tbeta + ((size_t)t * kNINT + locp) * 64;
            #pragma unroll
            for (int i = 0; i < 8; ++i)
                #pragma unroll
                for (int g = 0; g < 8; ++g) tb[i * 8 + g] = acc[i][g];
            int xv = x[nodep];
            float sg[8];
            #pragma unroll
            for (int g = 0; g < 8; ++g) sg[g] = 0.f;
            #pragma unroll
            for (int i = 0; i < 8; ++i)
                #pragma unroll
                for (int g = 0; g < 8; ++g) {
                    acc[i][g] *= sBm[(i * 128 + xv) * 8 + g];
                    sg[g] += acc[i][g];
                }
            float ig[8];
            #pragma unroll
            for (int g = 0; g < 8; ++g) ig[g] = 1.f / sg[g];
            float* bp = beta + (size_t)nodep * 64;
            #pragma unroll
            for (int i = 0; i < 8; ++i)
                #pragma unroll
                for (int g = 0; g < 8; ++g) bp[i * 8 + g] = acc[i][g] * ig[g];
        }
        __syncthreads();
    }

    // ---------- down pass ----------
    float ell[8];
    #pragma unroll
    for (int g = 0; g < 8; ++g) ell[g] = 0.f;

    // root: eps = beta (in place, no write needed); add Bm term for root
    if (tid == 0) {
        int node = t * kNPT;
        int xv = x[node];
        const float* bp = beta + (size_t)node * 64;
        #pragma unroll
        for (int c = 0; c < 8; ++c)
            #pragma unroll
            for (int g = 0; g < 8; ++g)
                ell[g] += bp[c * 8 + g] * sBm[(c * 128 + xv) * 8 + g];
    }
    // no barrier needed: root location is read-only below

    for (int d = 1; d <= 7; ++d) {
        int cbase = OFFS[d];
        int ccount = OFFS[d + 1] - OFFS[d];
        int pbase = OFFS[d - 1];
        for (int ci = tid; ci < ccount; ci += 256) {
            int locc = cbase + ci;
            int p = ci % 3;
            int locp = pbase + ci / 3;
            int nodec = t * kNPT + locc;
            const float* ep = beta + (size_t)(t * kNPT + locp) * 64;   // eps[pa]
            const float* tb = tbeta + ((size_t)t * kNINT + locp) * 64;
            float r[8][8];
            #pragma unroll
            for (int i = 0; i < 8; ++i)
                #pragma unroll
                for (int g = 0; g < 8; ++g)
                    r[i][g] = ep[i * 8 + g] / tb[i * 8 + g];
            float* bc = beta + (size_t)nodec * 64;
            float bj[8][8];
            #pragma unroll
            for (int j = 0; j < 8; ++j)
                #pragma unroll
                for (int g = 0; g < 8; ++g) bj[j][g] = bc[j * 8 + g];
            float esum[8], lg[8];
            #pragma unroll
            for (int g = 0; g < 8; ++g) { esum[g] = 0.f; lg[g] = 0.f; }
            #pragma unroll
            for (int g = 0; g < 8; ++g) {
                float spg = sSP[p * 8 + g];
                #pragma unroll
                for (int j = 0; j < 8; ++j) {
                    float s1 = 0.f, s2 = 0.f;
                    #pragma unroll
                    for (int i = 0; i < 8; ++i) {
                        int ai = ((i * 8 + j) * 3 + p) * 8 + g;
                        float a  = sA[ai];
                        float ra = r[i][g] * a;
                        s1 += ra;
                        s2 += ra * sLA[ai];
                    }
                    float base = spg * bj[j][g];
                    float ev = base * s1;
                    lg[g]   += base * s2;
                    bj[j][g] = ev;            // becomes eps[ch][j][g]
                    esum[g] += ev;
                }
                lg[g] += esum[g] * sLSP[p * 8 + g];
            }
            // write eps over beta (this node is dead as beta now)
            #pragma unroll
            for (int j = 0; j < 8; ++j)
                #pragma unroll
                for (int g = 0; g < 8; ++g) bc[j * 8 + g] = bj[j][g];
            // Bm term (all nodes)
            int xv = x[nodec];
            #pragma unroll
            for (int c = 0; c < 8; ++c)
                #pragma unroll
                for (int g = 0; g < 8; ++g)
                    lg[g] += bj[c][g] * sBm[(c * 128 + xv) * 8 + g];
            // leaf Pi term
            if (locc >= kLeaf0) {
                #pragma unroll
                for (int c = 0; c < 8; ++c)
                    #pragma unroll
                    for (int g = 0; g < 8; ++g)
                        lg[g] += bj[c][g] * sLPi[(c * 3 + p) * 8 + g];
            }
            #pragma unroll
            for (int g = 0; g < 8; ++g) ell[g] += lg[g];
        }
        __syncthreads();
    }

    // ---------- block reduction of ell ----------
    #pragma unroll
    for (int g = 0; g < 8; ++g) sred[tid * 8 + g] = ell[g];
    __syncthreads();
    for (int s = 128; s > 0; s >>= 1) {
        if (tid < s) {
            #pragma unroll
            for (int g = 0; g < 8; ++g)
                sred[tid * 8 + g] += sred[(tid + s) * 8 + g];
        }
        __syncthreads();
    }
    if (tid < 8) out[t * 8 + tid] = -sred[tid];
}

} // namespace

extern "C" void kernel_launch(void* const* d_in, const int* in_sizes, int n_in,
                              void* d_out, int out_size, void* d_ws, size_t ws_size,
                              hipStream_t stream) {
    const float* lamA  = (const float*)d_in[0];
    const float* lamB  = (const float*)d_in[1];
    const float* lamPi = (const float*)d_in[2];
    const float* lamSP = (const float*)d_in[3];
    const int*   x     = (const int*)d_in[4];
    // d_in[5]=pos, d_in[6]=leaves, d_in[7]=batch: derived analytically, unused.
    float* out   = (float*)d_out;
    float* beta  = (float*)d_ws;                           // DIM*64 floats
    float* tbeta = beta + (size_t)kNT * kNPT * 64;         // NT*1093*64 floats
    phtmm_kernel<<<dim3(kNT), dim3(256), 0, stream>>>(
        lamA, lamB, lamPi, lamSP, x, out, beta, tbeta);
}